// Round 21
// baseline (58.081 us; speedup 1.0000x reference)
//
#include <hip/hip_runtime.h>
#include <hip/hip_bf16.h>

#define B_ROWS 4096
#define DIMN 128
#define N2 8192
// z pre-scaled by sqrt(log2(e)/TEMP) so mfma output is already the exp2 arg
#define SQRT_CEXP 1.6986436f

using f32x4 = __attribute__((ext_vector_type(4))) float;
using i32x4 = __attribute__((ext_vector_type(4))) int;
using i32x8 = __attribute__((ext_vector_type(8))) int;
typedef long i64;

// f8f6f4-native tiled Z layout:
//   byte addr = Rtile*2048 + lane*32 + b,  lane = (k>>5)*16 + (row&15)
// = the 16x16x128 MFMA A/B fragment; load = 2x global_load_dwordx4.
//
// CONSTRAINT WEB (R9..R20) for the hand-counted-vmcnt pipeline:
//  - refill slot must never alias a LIVE slot (2-slot flip is sound)
//  - NEVER cap VGPR below natural alloc: spill VMEM corrupts vmcnt -> NaN
//  - NO stores inside the counted-vmcnt window (same corruption mechanism);
//    buffer epilogue outputs in registers, store after the final vmcnt(0)
//  - depth-2 prefetch, L1-share maps: neutral (R19/R20). Traffic is the wall.
//  - R21: Gram symmetry via circulant offset-tiles halves MFMA+traffic+exps.

// --- 1. normalize+scale+quantize into fragment layout; positives partials ---
__global__ __launch_bounds__(256) void normpos_k(const float* __restrict__ emb_i,
                                                 const float* __restrict__ emb_j,
                                                 i64* __restrict__ zt,
                                                 float* __restrict__ pospart,
                                                 float* __restrict__ out) {
    const int t = threadIdx.x;
    if (blockIdx.x == 0 && t == 0) out[0] = 0.f;
    const int lr = t >> 4;          // local row / pair
    const int s  = t & 15;          // 8-float slice (k = s*8..s*8+7)
    const int p  = blockIdx.x * 16 + lr;
    const float4* ai = (const float4*)(emb_i + (size_t)p * DIMN + s * 8);
    const float4* bj = (const float4*)(emb_j + (size_t)p * DIMN + s * 8);
    float4 a0 = ai[0], a1 = ai[1];
    float4 b0 = bj[0], b1 = bj[1];
    float sa = a0.x*a0.x + a0.y*a0.y + a0.z*a0.z + a0.w*a0.w
             + a1.x*a1.x + a1.y*a1.y + a1.z*a1.z + a1.w*a1.w;
    float sb = b0.x*b0.x + b0.y*b0.y + b0.z*b0.z + b0.w*b0.w
             + b1.x*b1.x + b1.y*b1.y + b1.z*b1.z + b1.w*b1.w;
    float dp = a0.x*b0.x + a0.y*b0.y + a0.z*b0.z + a0.w*b0.w
             + a1.x*b1.x + a1.y*b1.y + a1.z*b1.z + a1.w*b1.w;
    #pragma unroll
    for (int d = 1; d < 16; d <<= 1) {
        sa += __shfl_xor(sa, d);
        sb += __shfl_xor(sb, d);
        dp += __shfl_xor(dp, d);
    }
    float ia = __builtin_amdgcn_rsqf(fmaxf(sa, 1e-24f));
    float ib = __builtin_amdgcn_rsqf(fmaxf(sb, 1e-24f));
    float fa = ia * SQRT_CEXP, fb = ib * SQRT_CEXP;

    int wa0 = __builtin_amdgcn_cvt_pk_fp8_f32(a0.x * fa, a0.y * fa, 0, false);
    wa0     = __builtin_amdgcn_cvt_pk_fp8_f32(a0.z * fa, a0.w * fa, wa0, true);
    int wa1 = __builtin_amdgcn_cvt_pk_fp8_f32(a1.x * fa, a1.y * fa, 0, false);
    wa1     = __builtin_amdgcn_cvt_pk_fp8_f32(a1.z * fa, a1.w * fa, wa1, true);
    i64 qa = ((i64)(unsigned)wa1 << 32) | (unsigned)wa0;
    int wb0 = __builtin_amdgcn_cvt_pk_fp8_f32(b0.x * fb, b0.y * fb, 0, false);
    wb0     = __builtin_amdgcn_cvt_pk_fp8_f32(b0.z * fb, b0.w * fb, wb0, true);
    int wb1 = __builtin_amdgcn_cvt_pk_fp8_f32(b1.x * fb, b1.y * fb, 0, false);
    wb1     = __builtin_amdgcn_cvt_pk_fp8_f32(b1.z * fb, b1.w * fb, wb1, true);
    i64 qb = ((i64)(unsigned)wb1 << 32) | (unsigned)wb0;

    // fragment slot: k-block gk = s>>2, i64-in-lane = s&3, lane = gk*16+lr
    const int slot = ((s >> 2) * 16 + lr) * 4 + (s & 3);
    zt[(size_t)blockIdx.x * 256 + slot] = qa;            // Rtile = b
    zt[(size_t)(256 + blockIdx.x) * 256 + slot] = qb;    // Rtile = 256+b

    __shared__ float red[16];
    if (s == 0) red[lr] = dp * ia * ib;
    __syncthreads();
    if (t == 0) {
        float x = 0.f;
        #pragma unroll
        for (int i = 0; i < 16; ++i) x += red[i];
        pospart[blockIdx.x] = x;
    }
}

// --- step epilogue: ps += exp2(acc) rows; cs += col sums; optional diag mask -
template <bool MASK>
__device__ __forceinline__ void accum_step(const f32x4 (&acc)[2][2],
                                           float (&ps)[2][4], float (&cs)[2],
                                           int rb, int cb, int rq, int fr) {
    #pragma unroll
    for (int m = 0; m < 2; ++m)
        #pragma unroll
        for (int n = 0; n < 2; ++n)
            #pragma unroll
            for (int j = 0; j < 4; ++j) {
                float e = __builtin_amdgcn_exp2f(acc[m][n][j]);
                if (MASK) {
                    if (rb + m * 16 + rq + j == cb + n * 16 + fr) e = 0.f;
                }
                ps[m][j] += e;
                cs[n] += e;
            }
}

// --- 2a. SYMMETRIC circulant Gram (R18 body, 8 steps, rows+cols) -------------
// 1024 blocks x 256 thr. Block b: panel p=b>>2 (rows [32p,32p+32)), e=b&3.
// Wave w sweeps offset-tiles d_t = e*32+w*8+s (s=0..7), col cb=(rb+32*d_t)&8191.
// d_t=0: diag tile, rows only. d_t=1..127: rows + col-sums (symmetry).
// d_t=128 (self-transpose): extra rows-only step by (e==0,w==0) after the loop.
// Col-sums buffered in registers, stored AFTER the final vmcnt(0).
__global__ __launch_bounds__(256) void gram_sym_k(const char* __restrict__ zt,
                                                  float* __restrict__ rowpart,
                                                  float* __restrict__ colpart) {
    const int t = threadIdx.x;
    const int lane = t & 63;
    const int w = t >> 6;               // 0..3
    const int p = blockIdx.x >> 2;      // 32-row panel, 0..255
    const int e = blockIdx.x & 3;
    const int rb = p * 32;
    const int fr = lane & 15;
    const int rq = (lane >> 4) * 4;
    const int dt0 = e * 32 + w * 8;     // wave's first offset-tile

    const char* pa = zt + (size_t)(p * 2) * 2048 + lane * 32;
    auto bptr = [&](int dt) {
        return zt + (size_t)((rb + dt * 32) & 8191) * 128 + lane * 32;
    };

    // prologue: A (4 loads) + B slot0 (4 loads)
    i32x4 Alo[2], Ahi[2];
    #pragma unroll
    for (int m = 0; m < 2; ++m) {
        asm volatile("global_load_dwordx4 %0, %1, off"
                     : "=v"(Alo[m]) : "v"(pa + (size_t)m * 2048));
        asm volatile("global_load_dwordx4 %0, %1, off offset:16"
                     : "=v"(Ahi[m]) : "v"(pa + (size_t)m * 2048));
    }
    i32x4 Blo[2][2], Bhi[2][2];
    {
        const char* p0 = bptr(dt0);
        #pragma unroll
        for (int n = 0; n < 2; ++n) {
            asm volatile("global_load_dwordx4 %0, %1, off"
                         : "=v"(Blo[0][n]) : "v"(p0 + (size_t)n * 2048));
            asm volatile("global_load_dwordx4 %0, %1, off offset:16"
                         : "=v"(Bhi[0][n]) : "v"(p0 + (size_t)n * 2048));
        }
    }
    asm volatile("s_waitcnt vmcnt(4)" ::: "memory");    // A done; B0 in flight
    __builtin_amdgcn_sched_barrier(0);
    i32x8 A8[2];
    #pragma unroll
    for (int m = 0; m < 2; ++m)
        A8[m] = __builtin_shufflevector(Alo[m], Ahi[m], 0, 1, 2, 3, 4, 5, 6, 7);

    float ps[2][4] = {};
    float colsc0[8], colsc1[8];
    #pragma unroll
    for (int s = 0; s < 8; ++s) {
        if (s < 7) {                    // refill OTHER slot (d_t(s+1)), then wait
            const char* pn = bptr(dt0 + s + 1);
            #pragma unroll
            for (int n = 0; n < 2; ++n) {
                asm volatile("global_load_dwordx4 %0, %1, off"
                             : "=v"(Blo[(s + 1) & 1][n]) : "v"(pn + (size_t)n * 2048));
                asm volatile("global_load_dwordx4 %0, %1, off offset:16"
                             : "=v"(Bhi[(s + 1) & 1][n]) : "v"(pn + (size_t)n * 2048));
            }
            asm volatile("s_waitcnt vmcnt(4)" ::: "memory");
        } else {
            asm volatile("s_waitcnt vmcnt(0)" ::: "memory");
        }
        __builtin_amdgcn_sched_barrier(0);                    // rule #18 fence

        f32x4 acc[2][2] = {};
        __builtin_amdgcn_s_setprio(1);
        #pragma unroll
        for (int n = 0; n < 2; ++n) {
            i32x8 B8 = __builtin_shufflevector(Blo[s & 1][n], Bhi[s & 1][n],
                                               0, 1, 2, 3, 4, 5, 6, 7);
            #pragma unroll
            for (int m = 0; m < 2; ++m)
                acc[m][n] = __builtin_amdgcn_mfma_scale_f32_16x16x128_f8f6f4(
                    A8[m], B8, acc[m][n], 0, 0,          // cbsz=fp8, blgp=fp8
                    0, 0x7f7f7f7f, 0, 0x7f7f7f7f);       // unit scales (e8m0=127)
        }
        __builtin_amdgcn_s_setprio(0);

        const int cb = (rb + (dt0 + s) * 32) & 8191;
        float cs[2] = {0.f, 0.f};
        if (cb == rb) accum_step<true >(acc, ps, cs, rb, cb, rq, fr);
        else          accum_step<false>(acc, ps, cs, rb, cb, rq, fr);
        cs[0] += __shfl_xor(cs[0], 16); cs[0] += __shfl_xor(cs[0], 32);
        cs[1] += __shfl_xor(cs[1], 16); cs[1] += __shfl_xor(cs[1], 32);
        colsc0[s] = cs[0]; colsc1[s] = cs[1];
    }

    // extra step: d_t = 128 (self-transpose band), rows only, one wave per panel
    if (e == 0 && w == 0) {
        const char* pn = bptr(128);
        #pragma unroll
        for (int n = 0; n < 2; ++n) {
            asm volatile("global_load_dwordx4 %0, %1, off"
                         : "=v"(Blo[0][n]) : "v"(pn + (size_t)n * 2048));
            asm volatile("global_load_dwordx4 %0, %1, off offset:16"
                         : "=v"(Bhi[0][n]) : "v"(pn + (size_t)n * 2048));
        }
        asm volatile("s_waitcnt vmcnt(0)" ::: "memory");
        __builtin_amdgcn_sched_barrier(0);
        f32x4 acc[2][2] = {};
        #pragma unroll
        for (int n = 0; n < 2; ++n) {
            i32x8 B8 = __builtin_shufflevector(Blo[0][n], Bhi[0][n],
                                               0, 1, 2, 3, 4, 5, 6, 7);
            #pragma unroll
            for (int m = 0; m < 2; ++m)
                acc[m][n] = __builtin_amdgcn_mfma_scale_f32_16x16x128_f8f6f4(
                    A8[m], B8, acc[m][n], 0, 0, 0, 0x7f7f7f7f, 0, 0x7f7f7f7f);
        }
        float cs[2] = {0.f, 0.f};
        accum_step<false>(acc, ps, cs, rb, 0, rq, fr);   // rows only; cs unused
    }

    // col-part writes (write-once, no atomics) — AFTER all counted waits
    if (lane < 16) {
        #pragma unroll
        for (int s = 0; s < 8; ++s) {
            const int dt = dt0 + s;
            if (dt != 0) {
                const int cbb = (rb + dt * 32) & 8191;
                colpart[(size_t)dt * N2 + cbb + lane]      = colsc0[s];
                colpart[(size_t)dt * N2 + cbb + 16 + lane] = colsc1[s];
            }
        }
    }

    // row sums: 16-lane reduce, cross-wave LDS reduce, store this e's part
    #pragma unroll
    for (int m = 0; m < 2; ++m)
        #pragma unroll
        for (int j = 0; j < 4; ++j) {
            float v = ps[m][j];
            #pragma unroll
            for (int d = 1; d < 16; d <<= 1) v += __shfl_xor(v, d);
            ps[m][j] = v;
        }
    __shared__ float red[4][32];
    if (fr == 0) {
        #pragma unroll
        for (int m = 0; m < 2; ++m)
            #pragma unroll
            for (int j = 0; j < 4; ++j)
                red[w][m * 16 + rq + j] = ps[m][j];
    }
    __syncthreads();
    if (t < 32)
        rowpart[e * N2 + rb + t] = red[0][t] + red[1][t] + red[2][t] + red[3][t];
}

// --- 2b. FALLBACK: R18-proven full-sweep Gram (used if ws too small) ---------
__global__ __launch_bounds__(256) void gram_k(const char* __restrict__ zt,
                                              float* __restrict__ rowpart) {
    const int t = threadIdx.x;
    const int lane = t & 63;
    const int w = t >> 6;
    const int p = blockIdx.x >> 2;
    const int e = blockIdx.x & 3;
    const int rb = p * 32;
    const int fr = lane & 15;
    const int rq = (lane >> 4) * 4;

    const char* pa = zt + (size_t)(p * 2) * 2048 + lane * 32;
    const char* pb = zt + (size_t)(e * 128 + w * 32) * 2048 + lane * 32;

    i32x4 Alo[2], Ahi[2];
    #pragma unroll
    for (int m = 0; m < 2; ++m) {
        asm volatile("global_load_dwordx4 %0, %1, off"
                     : "=v"(Alo[m]) : "v"(pa + (size_t)m * 2048));
        asm volatile("global_load_dwordx4 %0, %1, off offset:16"
                     : "=v"(Ahi[m]) : "v"(pa + (size_t)m * 2048));
    }
    i32x4 Blo[2][2], Bhi[2][2];
    #pragma unroll
    for (int n = 0; n < 2; ++n) {
        asm volatile("global_load_dwordx4 %0, %1, off"
                     : "=v"(Blo[0][n]) : "v"(pb + (size_t)n * 2048));
        asm volatile("global_load_dwordx4 %0, %1, off offset:16"
                     : "=v"(Bhi[0][n]) : "v"(pb + (size_t)n * 2048));
    }
    asm volatile("s_waitcnt vmcnt(4)" ::: "memory");
    __builtin_amdgcn_sched_barrier(0);
    i32x8 A8[2];
    #pragma unroll
    for (int m = 0; m < 2; ++m)
        A8[m] = __builtin_shufflevector(Alo[m], Ahi[m], 0, 1, 2, 3, 4, 5, 6, 7);

    float ps[2][4] = {};
    #pragma unroll
    for (int s = 0; s < 16; ++s) {
        if (s < 15) {
            const char* pn = pb + (size_t)(s + 1) * 4096;
            #pragma unroll
            for (int n = 0; n < 2; ++n) {
                asm volatile("global_load_dwordx4 %0, %1, off"
                             : "=v"(Blo[(s + 1) & 1][n]) : "v"(pn + (size_t)n * 2048));
                asm volatile("global_load_dwordx4 %0, %1, off offset:16"
                             : "=v"(Bhi[(s + 1) & 1][n]) : "v"(pn + (size_t)n * 2048));
            }
            asm volatile("s_waitcnt vmcnt(4)" ::: "memory");
        } else {
            asm volatile("s_waitcnt vmcnt(0)" ::: "memory");
        }
        __builtin_amdgcn_sched_barrier(0);

        f32x4 acc[2][2] = {};
        __builtin_amdgcn_s_setprio(1);
        #pragma unroll
        for (int n = 0; n < 2; ++n) {
            i32x8 B8 = __builtin_shufflevector(Blo[s & 1][n], Bhi[s & 1][n],
                                               0, 1, 2, 3, 4, 5, 6, 7);
            #pragma unroll
            for (int m = 0; m < 2; ++m)
                acc[m][n] = __builtin_amdgcn_mfma_scale_f32_16x16x128_f8f6f4(
                    A8[m], B8, acc[m][n], 0, 0, 0, 0x7f7f7f7f, 0, 0x7f7f7f7f);
        }
        __builtin_amdgcn_s_setprio(0);

        const int cb = e * 2048 + w * 512 + s * 32;
        float cs[2] = {0.f, 0.f};
        if (cb == rb) accum_step<true >(acc, ps, cs, rb, cb, rq, fr);
        else          accum_step<false>(acc, ps, cs, rb, cb, rq, fr);
    }

    #pragma unroll
    for (int m = 0; m < 2; ++m)
        #pragma unroll
        for (int j = 0; j < 4; ++j) {
            float v = ps[m][j];
            #pragma unroll
            for (int d = 1; d < 16; d <<= 1) v += __shfl_xor(v, d);
            ps[m][j] = v;
        }
    __shared__ float red[4][32];
    if (fr == 0) {
        #pragma unroll
        for (int m = 0; m < 2; ++m)
            #pragma unroll
            for (int j = 0; j < 4; ++j)
                red[w][m * 16 + rq + j] = ps[m][j];
    }
    __syncthreads();
    if (t < 32)
        rowpart[e * N2 + rb + t] = red[0][t] + red[1][t] + red[2][t] + red[3][t];
}

// --- 3. finalize: denom = 4 rowparts + ncol colparts; distributed ------------
__global__ void finalize_k(const float* __restrict__ rowpart,
                           const float* __restrict__ colpart,
                           const float* __restrict__ pospart,
                           float* __restrict__ out, int ncol) {
    const int t = threadIdx.x;
    const int r = blockIdx.x * 1024 + t;
    float d = rowpart[r] + rowpart[N2 + r] + rowpart[2 * N2 + r] + rowpart[3 * N2 + r];
    for (int k = 1; k <= ncol; ++k) d += colpart[(size_t)k * N2 + r];
    float acc = __builtin_amdgcn_logf(d) * 0.6931471805599453f;   // ln
    if (blockIdx.x == 0 && t < 256) acc -= 4.0f * pospart[t];
    #pragma unroll
    for (int m = 32; m; m >>= 1) acc += __shfl_xor(acc, m);
    __shared__ float red[16];
    if ((t & 63) == 0) red[t >> 6] = acc;
    __syncthreads();
    if (t == 0) {
        float x = 0.f;
        #pragma unroll
        for (int i = 0; i < 16; ++i) x += red[i];
        atomicAdd(out, x * (1.0f / (2.0f * B_ROWS * 5.0f)));
    }
}

extern "C" void kernel_launch(void* const* d_in, const int* in_sizes, int n_in,
                              void* d_out, int out_size, void* d_ws, size_t ws_size,
                              hipStream_t stream) {
    const float* emb_i = (const float*)d_in[0];
    const float* emb_j = (const float*)d_in[1];
    i64* zt        = (i64*)d_ws;                                   // 1 MB tiled fp8
    float* rowpart = (float*)((char*)d_ws + (size_t)N2 * DIMN);    // 128 KB
    float* pospart = rowpart + 4 * N2;                             // 1 KB
    float* colpart = pospart + 256;                                // 4 MB
    const size_t need = (size_t)N2 * DIMN + (4 * N2 + 256 + 128 * N2) * sizeof(float);
    const bool sym = ws_size >= need;

    normpos_k<<<256, 256, 0, stream>>>(emb_i, emb_j, zt, pospart, (float*)d_out);
    if (sym) {
        gram_sym_k<<<1024, 256, 0, stream>>>((const char*)zt, rowpart, colpart);
        finalize_k<<<8, 1024, 0, stream>>>(rowpart, colpart, pospart, (float*)d_out, 127);
    } else {
        gram_k<<<1024, 256, 0, stream>>>((const char*)zt, rowpart);
        finalize_k<<<8, 1024, 0, stream>>>(rowpart, colpart, pospart, (float*)d_out, 0);
    }
}

// Round 22
// 31.308 us; speedup vs baseline: 1.8551x; 1.8551x over previous
//
#include <hip/hip_runtime.h>
#include <hip/hip_bf16.h>

#define B_ROWS 4096
#define DIMN 128
#define N2 8192
// z pre-scaled by sqrt(log2(e)/TEMP) so mfma output is already the exp2 arg
#define SQRT_CEXP 1.6986436f

using f32x4 = __attribute__((ext_vector_type(4))) float;
using i32x4 = __attribute__((ext_vector_type(4))) int;
using i32x8 = __attribute__((ext_vector_type(8))) int;
typedef long i64;

// f8f6f4-native tiled Z layout:
//   byte addr = Rtile*2048 + lane*32 + b,  lane = (k>>5)*16 + (row&15)
// = the 16x16x128 MFMA A/B fragment; load = 2x global_load_dwordx4.
//
// CONSTRAINT WEB (R9..R21):
//  - refill slot must never alias a LIVE slot (2-slot flip is sound)
//  - NEVER cap VGPR below natural alloc: spill VMEM corrupts vmcnt -> NaN
//  - NO stores inside the counted-vmcnt window; buffer in regs, store after
//  - depth-2 prefetch, L1-share maps: neutral. Traffic was the wall ->
//    R21 circulant symmetry halves MFMA+traffic+exps (coverage PROVEN, absmax 0)
//  - R22: finalize had a 127-deep dependent add chain on 8 blocks (~26us!);
//    fix = 8 independent accumulators + 32 blocks.

// --- 1. normalize+scale+quantize into fragment layout; positives partials ---
__global__ __launch_bounds__(256) void normpos_k(const float* __restrict__ emb_i,
                                                 const float* __restrict__ emb_j,
                                                 i64* __restrict__ zt,
                                                 float* __restrict__ pospart,
                                                 float* __restrict__ out) {
    const int t = threadIdx.x;
    if (blockIdx.x == 0 && t == 0) out[0] = 0.f;
    const int lr = t >> 4;          // local row / pair
    const int s  = t & 15;          // 8-float slice (k = s*8..s*8+7)
    const int p  = blockIdx.x * 16 + lr;
    const float4* ai = (const float4*)(emb_i + (size_t)p * DIMN + s * 8);
    const float4* bj = (const float4*)(emb_j + (size_t)p * DIMN + s * 8);
    float4 a0 = ai[0], a1 = ai[1];
    float4 b0 = bj[0], b1 = bj[1];
    float sa = a0.x*a0.x + a0.y*a0.y + a0.z*a0.z + a0.w*a0.w
             + a1.x*a1.x + a1.y*a1.y + a1.z*a1.z + a1.w*a1.w;
    float sb = b0.x*b0.x + b0.y*b0.y + b0.z*b0.z + b0.w*b0.w
             + b1.x*b1.x + b1.y*b1.y + b1.z*b1.z + b1.w*b1.w;
    float dp = a0.x*b0.x + a0.y*b0.y + a0.z*b0.z + a0.w*b0.w
             + a1.x*b1.x + a1.y*b1.y + a1.z*b1.z + a1.w*b1.w;
    #pragma unroll
    for (int d = 1; d < 16; d <<= 1) {
        sa += __shfl_xor(sa, d);
        sb += __shfl_xor(sb, d);
        dp += __shfl_xor(dp, d);
    }
    float ia = __builtin_amdgcn_rsqf(fmaxf(sa, 1e-24f));
    float ib = __builtin_amdgcn_rsqf(fmaxf(sb, 1e-24f));
    float fa = ia * SQRT_CEXP, fb = ib * SQRT_CEXP;

    int wa0 = __builtin_amdgcn_cvt_pk_fp8_f32(a0.x * fa, a0.y * fa, 0, false);
    wa0     = __builtin_amdgcn_cvt_pk_fp8_f32(a0.z * fa, a0.w * fa, wa0, true);
    int wa1 = __builtin_amdgcn_cvt_pk_fp8_f32(a1.x * fa, a1.y * fa, 0, false);
    wa1     = __builtin_amdgcn_cvt_pk_fp8_f32(a1.z * fa, a1.w * fa, wa1, true);
    i64 qa = ((i64)(unsigned)wa1 << 32) | (unsigned)wa0;
    int wb0 = __builtin_amdgcn_cvt_pk_fp8_f32(b0.x * fb, b0.y * fb, 0, false);
    wb0     = __builtin_amdgcn_cvt_pk_fp8_f32(b0.z * fb, b0.w * fb, wb0, true);
    int wb1 = __builtin_amdgcn_cvt_pk_fp8_f32(b1.x * fb, b1.y * fb, 0, false);
    wb1     = __builtin_amdgcn_cvt_pk_fp8_f32(b1.z * fb, b1.w * fb, wb1, true);
    i64 qb = ((i64)(unsigned)wb1 << 32) | (unsigned)wb0;

    // fragment slot: k-block gk = s>>2, i64-in-lane = s&3, lane = gk*16+lr
    const int slot = ((s >> 2) * 16 + lr) * 4 + (s & 3);
    zt[(size_t)blockIdx.x * 256 + slot] = qa;            // Rtile = b
    zt[(size_t)(256 + blockIdx.x) * 256 + slot] = qb;    // Rtile = 256+b

    __shared__ float red[16];
    if (s == 0) red[lr] = dp * ia * ib;
    __syncthreads();
    if (t == 0) {
        float x = 0.f;
        #pragma unroll
        for (int i = 0; i < 16; ++i) x += red[i];
        pospart[blockIdx.x] = x;
    }
}

// --- step epilogue: ps += exp2(acc) rows; cs += col sums; optional diag mask -
template <bool MASK>
__device__ __forceinline__ void accum_step(const f32x4 (&acc)[2][2],
                                           float (&ps)[2][4], float (&cs)[2],
                                           int rb, int cb, int rq, int fr) {
    #pragma unroll
    for (int m = 0; m < 2; ++m)
        #pragma unroll
        for (int n = 0; n < 2; ++n)
            #pragma unroll
            for (int j = 0; j < 4; ++j) {
                float e = __builtin_amdgcn_exp2f(acc[m][n][j]);
                if (MASK) {
                    if (rb + m * 16 + rq + j == cb + n * 16 + fr) e = 0.f;
                }
                ps[m][j] += e;
                cs[n] += e;
            }
}

// --- 2. SYMMETRIC circulant Gram (R21-proven, byte-identical) ----------------
// 1024 blocks x 256 thr. Block b: panel p=b>>2 (rows [32p,32p+32)), e=b&3.
// Wave w sweeps offset-tiles d_t = e*32+w*8+s (s=0..7), col cb=(rb+32*d_t)&8191.
// d_t=0: diag tile, rows only. d_t=1..127: rows + col-sums (symmetry).
// d_t=128 (self-transpose): extra rows-only step by (e==0,w==0) after the loop.
// Col-sums buffered in registers, stored AFTER the final vmcnt(0).
__global__ __launch_bounds__(256) void gram_sym_k(const char* __restrict__ zt,
                                                  float* __restrict__ rowpart,
                                                  float* __restrict__ colpart) {
    const int t = threadIdx.x;
    const int lane = t & 63;
    const int w = t >> 6;               // 0..3
    const int p = blockIdx.x >> 2;      // 32-row panel, 0..255
    const int e = blockIdx.x & 3;
    const int rb = p * 32;
    const int fr = lane & 15;
    const int rq = (lane >> 4) * 4;
    const int dt0 = e * 32 + w * 8;     // wave's first offset-tile

    const char* pa = zt + (size_t)(p * 2) * 2048 + lane * 32;
    auto bptr = [&](int dt) {
        return zt + (size_t)((rb + dt * 32) & 8191) * 128 + lane * 32;
    };

    // prologue: A (4 loads) + B slot0 (4 loads)
    i32x4 Alo[2], Ahi[2];
    #pragma unroll
    for (int m = 0; m < 2; ++m) {
        asm volatile("global_load_dwordx4 %0, %1, off"
                     : "=v"(Alo[m]) : "v"(pa + (size_t)m * 2048));
        asm volatile("global_load_dwordx4 %0, %1, off offset:16"
                     : "=v"(Ahi[m]) : "v"(pa + (size_t)m * 2048));
    }
    i32x4 Blo[2][2], Bhi[2][2];
    {
        const char* p0 = bptr(dt0);
        #pragma unroll
        for (int n = 0; n < 2; ++n) {
            asm volatile("global_load_dwordx4 %0, %1, off"
                         : "=v"(Blo[0][n]) : "v"(p0 + (size_t)n * 2048));
            asm volatile("global_load_dwordx4 %0, %1, off offset:16"
                         : "=v"(Bhi[0][n]) : "v"(p0 + (size_t)n * 2048));
        }
    }
    asm volatile("s_waitcnt vmcnt(4)" ::: "memory");    // A done; B0 in flight
    __builtin_amdgcn_sched_barrier(0);
    i32x8 A8[2];
    #pragma unroll
    for (int m = 0; m < 2; ++m)
        A8[m] = __builtin_shufflevector(Alo[m], Ahi[m], 0, 1, 2, 3, 4, 5, 6, 7);

    float ps[2][4] = {};
    float colsc0[8], colsc1[8];
    #pragma unroll
    for (int s = 0; s < 8; ++s) {
        if (s < 7) {                    // refill OTHER slot (d_t(s+1)), then wait
            const char* pn = bptr(dt0 + s + 1);
            #pragma unroll
            for (int n = 0; n < 2; ++n) {
                asm volatile("global_load_dwordx4 %0, %1, off"
                             : "=v"(Blo[(s + 1) & 1][n]) : "v"(pn + (size_t)n * 2048));
                asm volatile("global_load_dwordx4 %0, %1, off offset:16"
                             : "=v"(Bhi[(s + 1) & 1][n]) : "v"(pn + (size_t)n * 2048));
            }
            asm volatile("s_waitcnt vmcnt(4)" ::: "memory");
        } else {
            asm volatile("s_waitcnt vmcnt(0)" ::: "memory");
        }
        __builtin_amdgcn_sched_barrier(0);                    // rule #18 fence

        f32x4 acc[2][2] = {};
        __builtin_amdgcn_s_setprio(1);
        #pragma unroll
        for (int n = 0; n < 2; ++n) {
            i32x8 B8 = __builtin_shufflevector(Blo[s & 1][n], Bhi[s & 1][n],
                                               0, 1, 2, 3, 4, 5, 6, 7);
            #pragma unroll
            for (int m = 0; m < 2; ++m)
                acc[m][n] = __builtin_amdgcn_mfma_scale_f32_16x16x128_f8f6f4(
                    A8[m], B8, acc[m][n], 0, 0,          // cbsz=fp8, blgp=fp8
                    0, 0x7f7f7f7f, 0, 0x7f7f7f7f);       // unit scales (e8m0=127)
        }
        __builtin_amdgcn_s_setprio(0);

        const int cb = (rb + (dt0 + s) * 32) & 8191;
        float cs[2] = {0.f, 0.f};
        if (cb == rb) accum_step<true >(acc, ps, cs, rb, cb, rq, fr);
        else          accum_step<false>(acc, ps, cs, rb, cb, rq, fr);
        cs[0] += __shfl_xor(cs[0], 16); cs[0] += __shfl_xor(cs[0], 32);
        cs[1] += __shfl_xor(cs[1], 16); cs[1] += __shfl_xor(cs[1], 32);
        colsc0[s] = cs[0]; colsc1[s] = cs[1];
    }

    // extra step: d_t = 128 (self-transpose band), rows only, one wave per panel
    if (e == 0 && w == 0) {
        const char* pn = bptr(128);
        #pragma unroll
        for (int n = 0; n < 2; ++n) {
            asm volatile("global_load_dwordx4 %0, %1, off"
                         : "=v"(Blo[0][n]) : "v"(pn + (size_t)n * 2048));
            asm volatile("global_load_dwordx4 %0, %1, off offset:16"
                         : "=v"(Bhi[0][n]) : "v"(pn + (size_t)n * 2048));
        }
        asm volatile("s_waitcnt vmcnt(0)" ::: "memory");
        __builtin_amdgcn_sched_barrier(0);
        f32x4 acc[2][2] = {};
        #pragma unroll
        for (int n = 0; n < 2; ++n) {
            i32x8 B8 = __builtin_shufflevector(Blo[0][n], Bhi[0][n],
                                               0, 1, 2, 3, 4, 5, 6, 7);
            #pragma unroll
            for (int m = 0; m < 2; ++m)
                acc[m][n] = __builtin_amdgcn_mfma_scale_f32_16x16x128_f8f6f4(
                    A8[m], B8, acc[m][n], 0, 0, 0, 0x7f7f7f7f, 0, 0x7f7f7f7f);
        }
        float cs[2] = {0.f, 0.f};
        accum_step<false>(acc, ps, cs, rb, 0, rq, fr);   // rows only; cs unused
    }

    // col-part writes (write-once, no atomics) — AFTER all counted waits
    if (lane < 16) {
        #pragma unroll
        for (int s = 0; s < 8; ++s) {
            const int dt = dt0 + s;
            if (dt != 0) {
                const int cbb = (rb + dt * 32) & 8191;
                colpart[(size_t)dt * N2 + cbb + lane]      = colsc0[s];
                colpart[(size_t)dt * N2 + cbb + 16 + lane] = colsc1[s];
            }
        }
    }

    // row sums: 16-lane reduce, cross-wave LDS reduce, store this e's part
    #pragma unroll
    for (int m = 0; m < 2; ++m)
        #pragma unroll
        for (int j = 0; j < 4; ++j) {
            float v = ps[m][j];
            #pragma unroll
            for (int d = 1; d < 16; d <<= 1) v += __shfl_xor(v, d);
            ps[m][j] = v;
        }
    __shared__ float red[4][32];
    if (fr == 0) {
        #pragma unroll
        for (int m = 0; m < 2; ++m)
            #pragma unroll
            for (int j = 0; j < 4; ++j)
                red[w][m * 16 + rq + j] = ps[m][j];
    }
    __syncthreads();
    if (t < 32)
        rowpart[e * N2 + rb + t] = red[0][t] + red[1][t] + red[2][t] + red[3][t];
}

// --- 3. finalize: 32 blocks x 256 thr, 8 independent accumulators ------------
// (R21 regression: 127-deep dependent add chain on 8 blocks = ~26us. Fixed.)
__global__ __launch_bounds__(256) void finalize_k(const float* __restrict__ rowpart,
                                                  const float* __restrict__ colpart,
                                                  const float* __restrict__ pospart,
                                                  float* __restrict__ out) {
    const int t = threadIdx.x;
    const int r = blockIdx.x * 256 + t;          // one row per thread
    float a0 = rowpart[r], a1 = rowpart[N2 + r];
    float a2 = rowpart[2 * N2 + r], a3 = rowpart[3 * N2 + r];
    float a4 = 0.f, a5 = 0.f, a6 = 0.f, a7 = 0.f;
    const float* cp = colpart + r;
    // k = 1..120: 15 rounds of 8 independent loads
    for (int k = 1; k <= 113; k += 8) {
        a0 += cp[(size_t)(k + 0) * N2];
        a1 += cp[(size_t)(k + 1) * N2];
        a2 += cp[(size_t)(k + 2) * N2];
        a3 += cp[(size_t)(k + 3) * N2];
        a4 += cp[(size_t)(k + 4) * N2];
        a5 += cp[(size_t)(k + 5) * N2];
        a6 += cp[(size_t)(k + 6) * N2];
        a7 += cp[(size_t)(k + 7) * N2];
    }
    // k = 121..127
    a0 += cp[(size_t)121 * N2]; a1 += cp[(size_t)122 * N2];
    a2 += cp[(size_t)123 * N2]; a3 += cp[(size_t)124 * N2];
    a4 += cp[(size_t)125 * N2]; a5 += cp[(size_t)126 * N2];
    a6 += cp[(size_t)127 * N2];
    float d = ((a0 + a1) + (a2 + a3)) + ((a4 + a5) + (a6 + a7));

    float acc = __builtin_amdgcn_logf(d) * 0.6931471805599453f;   // ln
    if (blockIdx.x == 0) acc -= 4.0f * pospart[t];                // 256 pospart entries
    #pragma unroll
    for (int m = 32; m; m >>= 1) acc += __shfl_xor(acc, m);
    __shared__ float red[4];
    if ((t & 63) == 0) red[t >> 6] = acc;
    __syncthreads();
    if (t == 0)
        atomicAdd(out, (red[0] + red[1] + red[2] + red[3]) *
                       (1.0f / (2.0f * B_ROWS * 5.0f)));
}

extern "C" void kernel_launch(void* const* d_in, const int* in_sizes, int n_in,
                              void* d_out, int out_size, void* d_ws, size_t ws_size,
                              hipStream_t stream) {
    const float* emb_i = (const float*)d_in[0];
    const float* emb_j = (const float*)d_in[1];
    i64* zt        = (i64*)d_ws;                                   // 1 MB tiled fp8
    float* rowpart = (float*)((char*)d_ws + (size_t)N2 * DIMN);    // 128 KB
    float* pospart = rowpart + 4 * N2;                             // 1 KB
    float* colpart = pospart + 256;                                // 4 MB

    normpos_k<<<256, 256, 0, stream>>>(emb_i, emb_j, zt, pospart, (float*)d_out);
    gram_sym_k<<<1024, 256, 0, stream>>>((const char*)zt, rowpart, colpart);
    finalize_k<<<32, 256, 0, stream>>>(rowpart, colpart, pospart, (float*)d_out);
}

// Round 23
// 30.986 us; speedup vs baseline: 1.8744x; 1.0104x over previous
//
#include <hip/hip_runtime.h>
#include <hip/hip_bf16.h>

#define B_ROWS 4096
#define DIMN 128
#define N2 8192
// z pre-scaled by sqrt(log2(e)/TEMP) so mfma output is already the exp2 arg
#define SQRT_CEXP 1.6986436f

using f32x4 = __attribute__((ext_vector_type(4))) float;
using i32x4 = __attribute__((ext_vector_type(4))) int;
using i32x8 = __attribute__((ext_vector_type(8))) int;
typedef long i64;

// f8f6f4-native tiled Z layout:
//   byte addr = Rtile*2048 + lane*32 + b,  lane = (k>>5)*16 + (row&15)
// = the 16x16x128 MFMA A/B fragment; load = 2x global_load_dwordx4.
//
// CONSTRAINT WEB (R9..R22):
//  - refill slot must never alias a LIVE slot (2-slot flip is sound)
//  - NEVER cap VGPR below natural alloc: spill VMEM corrupts vmcnt -> NaN
//  - NO global stores in the counted-vmcnt window; LDS (ds_write) is SAFE
//    (lgkmcnt, not vmcnt) — use LDS to buffer epilogue outputs, not registers
//  - VGPR CLIFF at 128 (waves/SIMD halve): R22's colsc[16] regs likely crossed
//    it -> 2 waves/SIMD -> sym slower than full. R23: col-sums -> LDS slab.
//  - circulant symmetry coverage PROVEN correct (R21/R22 absmax 0.0)

// --- 1. normalize+scale+quantize into fragment layout; positives partials ---
__global__ __launch_bounds__(256) void normpos_k(const float* __restrict__ emb_i,
                                                 const float* __restrict__ emb_j,
                                                 i64* __restrict__ zt,
                                                 float* __restrict__ pospart,
                                                 float* __restrict__ out) {
    const int t = threadIdx.x;
    if (blockIdx.x == 0 && t == 0) out[0] = 0.f;
    const int lr = t >> 4;          // local row / pair
    const int s  = t & 15;          // 8-float slice (k = s*8..s*8+7)
    const int p  = blockIdx.x * 16 + lr;
    const float4* ai = (const float4*)(emb_i + (size_t)p * DIMN + s * 8);
    const float4* bj = (const float4*)(emb_j + (size_t)p * DIMN + s * 8);
    float4 a0 = ai[0], a1 = ai[1];
    float4 b0 = bj[0], b1 = bj[1];
    float sa = a0.x*a0.x + a0.y*a0.y + a0.z*a0.z + a0.w*a0.w
             + a1.x*a1.x + a1.y*a1.y + a1.z*a1.z + a1.w*a1.w;
    float sb = b0.x*b0.x + b0.y*b0.y + b0.z*b0.z + b0.w*b0.w
             + b1.x*b1.x + b1.y*b1.y + b1.z*b1.z + b1.w*b1.w;
    float dp = a0.x*b0.x + a0.y*b0.y + a0.z*b0.z + a0.w*b0.w
             + a1.x*b1.x + a1.y*b1.y + a1.z*b1.z + a1.w*b1.w;
    #pragma unroll
    for (int d = 1; d < 16; d <<= 1) {
        sa += __shfl_xor(sa, d);
        sb += __shfl_xor(sb, d);
        dp += __shfl_xor(dp, d);
    }
    float ia = __builtin_amdgcn_rsqf(fmaxf(sa, 1e-24f));
    float ib = __builtin_amdgcn_rsqf(fmaxf(sb, 1e-24f));
    float fa = ia * SQRT_CEXP, fb = ib * SQRT_CEXP;

    int wa0 = __builtin_amdgcn_cvt_pk_fp8_f32(a0.x * fa, a0.y * fa, 0, false);
    wa0     = __builtin_amdgcn_cvt_pk_fp8_f32(a0.z * fa, a0.w * fa, wa0, true);
    int wa1 = __builtin_amdgcn_cvt_pk_fp8_f32(a1.x * fa, a1.y * fa, 0, false);
    wa1     = __builtin_amdgcn_cvt_pk_fp8_f32(a1.z * fa, a1.w * fa, wa1, true);
    i64 qa = ((i64)(unsigned)wa1 << 32) | (unsigned)wa0;
    int wb0 = __builtin_amdgcn_cvt_pk_fp8_f32(b0.x * fb, b0.y * fb, 0, false);
    wb0     = __builtin_amdgcn_cvt_pk_fp8_f32(b0.z * fb, b0.w * fb, wb0, true);
    int wb1 = __builtin_amdgcn_cvt_pk_fp8_f32(b1.x * fb, b1.y * fb, 0, false);
    wb1     = __builtin_amdgcn_cvt_pk_fp8_f32(b1.z * fb, b1.w * fb, wb1, true);
    i64 qb = ((i64)(unsigned)wb1 << 32) | (unsigned)wb0;

    // fragment slot: k-block gk = s>>2, i64-in-lane = s&3, lane = gk*16+lr
    const int slot = ((s >> 2) * 16 + lr) * 4 + (s & 3);
    zt[(size_t)blockIdx.x * 256 + slot] = qa;            // Rtile = b
    zt[(size_t)(256 + blockIdx.x) * 256 + slot] = qb;    // Rtile = 256+b

    __shared__ float red[16];
    if (s == 0) red[lr] = dp * ia * ib;
    __syncthreads();
    if (t == 0) {
        float x = 0.f;
        #pragma unroll
        for (int i = 0; i < 16; ++i) x += red[i];
        pospart[blockIdx.x] = x;
    }
}

// --- step epilogue: ps += exp2(acc) rows; cs += col sums; optional diag mask -
template <bool MASK>
__device__ __forceinline__ void accum_step(const f32x4 (&acc)[2][2],
                                           float (&ps)[2][4], float (&cs)[2],
                                           int rb, int cb, int rq, int fr) {
    #pragma unroll
    for (int m = 0; m < 2; ++m)
        #pragma unroll
        for (int n = 0; n < 2; ++n)
            #pragma unroll
            for (int j = 0; j < 4; ++j) {
                float e = __builtin_amdgcn_exp2f(acc[m][n][j]);
                if (MASK) {
                    if (rb + m * 16 + rq + j == cb + n * 16 + fr) e = 0.f;
                }
                ps[m][j] += e;
                cs[n] += e;
            }
}

// --- 2. SYMMETRIC circulant Gram, col-sums via LDS (VGPR-cliff fix) ----------
// 1024 blocks x 256 thr. Block b: panel p=b>>2 (rows [32p,32p+32)), e=b&3.
// Wave w sweeps offset-tiles d_t = e*32+w*8+s (s=0..7), col cb=(rb+32*d_t)&8191.
// d_t=0: diag tile, rows only. d_t=1..127: rows + col-sums (symmetry).
// d_t=128 (self-transpose): extra rows-only step by (e==0,w==0) after the loop.
// Col-sums go to an LDS slab per step (ds_write = lgkmcnt, vmcnt-safe),
// flushed to colpart AFTER the final vmcnt(0) + barrier.
__global__ __launch_bounds__(256) void gram_sym_k(const char* __restrict__ zt,
                                                  float* __restrict__ rowpart,
                                                  float* __restrict__ colpart) {
    __shared__ float colbuf[4][8][32];   // [wave][step][col-in-tile], 4 KB
    const int t = threadIdx.x;
    const int lane = t & 63;
    const int w = t >> 6;               // 0..3
    const int p = blockIdx.x >> 2;      // 32-row panel, 0..255
    const int e = blockIdx.x & 3;
    const int rb = p * 32;
    const int fr = lane & 15;
    const int rq = (lane >> 4) * 4;
    const int dt0 = e * 32 + w * 8;     // wave's first offset-tile

    const char* pa = zt + (size_t)(p * 2) * 2048 + lane * 32;
    auto bptr = [&](int dt) {
        return zt + (size_t)((rb + dt * 32) & 8191) * 128 + lane * 32;
    };

    // prologue: A (4 loads) + B slot0 (4 loads)
    i32x4 Alo[2], Ahi[2];
    #pragma unroll
    for (int m = 0; m < 2; ++m) {
        asm volatile("global_load_dwordx4 %0, %1, off"
                     : "=v"(Alo[m]) : "v"(pa + (size_t)m * 2048));
        asm volatile("global_load_dwordx4 %0, %1, off offset:16"
                     : "=v"(Ahi[m]) : "v"(pa + (size_t)m * 2048));
    }
    i32x4 Blo[2][2], Bhi[2][2];
    {
        const char* p0 = bptr(dt0);
        #pragma unroll
        for (int n = 0; n < 2; ++n) {
            asm volatile("global_load_dwordx4 %0, %1, off"
                         : "=v"(Blo[0][n]) : "v"(p0 + (size_t)n * 2048));
            asm volatile("global_load_dwordx4 %0, %1, off offset:16"
                         : "=v"(Bhi[0][n]) : "v"(p0 + (size_t)n * 2048));
        }
    }
    asm volatile("s_waitcnt vmcnt(4)" ::: "memory");    // A done; B0 in flight
    __builtin_amdgcn_sched_barrier(0);
    i32x8 A8[2];
    #pragma unroll
    for (int m = 0; m < 2; ++m)
        A8[m] = __builtin_shufflevector(Alo[m], Ahi[m], 0, 1, 2, 3, 4, 5, 6, 7);

    float ps[2][4] = {};
    #pragma unroll
    for (int s = 0; s < 8; ++s) {
        if (s < 7) {                    // refill OTHER slot (d_t(s+1)), then wait
            const char* pn = bptr(dt0 + s + 1);
            #pragma unroll
            for (int n = 0; n < 2; ++n) {
                asm volatile("global_load_dwordx4 %0, %1, off"
                             : "=v"(Blo[(s + 1) & 1][n]) : "v"(pn + (size_t)n * 2048));
                asm volatile("global_load_dwordx4 %0, %1, off offset:16"
                             : "=v"(Bhi[(s + 1) & 1][n]) : "v"(pn + (size_t)n * 2048));
            }
            asm volatile("s_waitcnt vmcnt(4)" ::: "memory");
        } else {
            asm volatile("s_waitcnt vmcnt(0)" ::: "memory");
        }
        __builtin_amdgcn_sched_barrier(0);                    // rule #18 fence

        f32x4 acc[2][2] = {};
        __builtin_amdgcn_s_setprio(1);
        #pragma unroll
        for (int n = 0; n < 2; ++n) {
            i32x8 B8 = __builtin_shufflevector(Blo[s & 1][n], Bhi[s & 1][n],
                                               0, 1, 2, 3, 4, 5, 6, 7);
            #pragma unroll
            for (int m = 0; m < 2; ++m)
                acc[m][n] = __builtin_amdgcn_mfma_scale_f32_16x16x128_f8f6f4(
                    A8[m], B8, acc[m][n], 0, 0,          // cbsz=fp8, blgp=fp8
                    0, 0x7f7f7f7f, 0, 0x7f7f7f7f);       // unit scales (e8m0=127)
        }
        __builtin_amdgcn_s_setprio(0);

        const int cb = (rb + (dt0 + s) * 32) & 8191;
        float cs[2] = {0.f, 0.f};
        if (cb == rb) accum_step<true >(acc, ps, cs, rb, cb, rq, fr);
        else          accum_step<false>(acc, ps, cs, rb, cb, rq, fr);
        cs[0] += __shfl_xor(cs[0], 16); cs[0] += __shfl_xor(cs[0], 32);
        cs[1] += __shfl_xor(cs[1], 16); cs[1] += __shfl_xor(cs[1], 32);
        if (lane < 16) {                // LDS buffer (lgkmcnt — vmcnt-safe)
            colbuf[w][s][fr]      = cs[0];
            colbuf[w][s][16 + fr] = cs[1];
        }
    }

    // extra step: d_t = 128 (self-transpose band), rows only, one wave per panel
    if (e == 0 && w == 0) {
        const char* pn = bptr(128);
        #pragma unroll
        for (int n = 0; n < 2; ++n) {
            asm volatile("global_load_dwordx4 %0, %1, off"
                         : "=v"(Blo[0][n]) : "v"(pn + (size_t)n * 2048));
            asm volatile("global_load_dwordx4 %0, %1, off offset:16"
                         : "=v"(Bhi[0][n]) : "v"(pn + (size_t)n * 2048));
        }
        asm volatile("s_waitcnt vmcnt(0)" ::: "memory");
        __builtin_amdgcn_sched_barrier(0);
        f32x4 acc[2][2] = {};
        #pragma unroll
        for (int n = 0; n < 2; ++n) {
            i32x8 B8 = __builtin_shufflevector(Blo[0][n], Bhi[0][n],
                                               0, 1, 2, 3, 4, 5, 6, 7);
            #pragma unroll
            for (int m = 0; m < 2; ++m)
                acc[m][n] = __builtin_amdgcn_mfma_scale_f32_16x16x128_f8f6f4(
                    A8[m], B8, acc[m][n], 0, 0, 0, 0x7f7f7f7f, 0, 0x7f7f7f7f);
        }
        float cs[2] = {0.f, 0.f};
        accum_step<false>(acc, ps, cs, rb, 0, rq, fr);   // rows only; cs unused
    }

    // row sums: 16-lane reduce, cross-wave LDS reduce
    #pragma unroll
    for (int m = 0; m < 2; ++m)
        #pragma unroll
        for (int j = 0; j < 4; ++j) {
            float v = ps[m][j];
            #pragma unroll
            for (int d = 1; d < 16; d <<= 1) v += __shfl_xor(v, d);
            ps[m][j] = v;
        }
    __shared__ float red[4][32];
    if (fr == 0) {
        #pragma unroll
        for (int m = 0; m < 2; ++m)
            #pragma unroll
            for (int j = 0; j < 4; ++j)
                red[w][m * 16 + rq + j] = ps[m][j];
    }
    __syncthreads();
    if (t < 32)
        rowpart[e * N2 + rb + t] = red[0][t] + red[1][t] + red[2][t] + red[3][t];

    // flush col-partials: 1024 values by 256 threads (4 each), write-once
    #pragma unroll
    for (int i = 0; i < 4; ++i) {
        const int idx = t + i * 256;          // = (w*8+s)*32 + c
        const int ws = idx >> 5, c = idx & 31;
        const int dt = e * 32 + ws;
        if (dt != 0) {
            const int cbb = (rb + dt * 32) & 8191;
            colpart[(size_t)dt * N2 + cbb + c] = colbuf[ws >> 3][ws & 7][c];
        }
    }
}

// --- 3. finalize: 32 blocks x 256 thr, 8 independent accumulators ------------
__global__ __launch_bounds__(256) void finalize_k(const float* __restrict__ rowpart,
                                                  const float* __restrict__ colpart,
                                                  const float* __restrict__ pospart,
                                                  float* __restrict__ out) {
    const int t = threadIdx.x;
    const int r = blockIdx.x * 256 + t;          // one row per thread
    float a0 = rowpart[r], a1 = rowpart[N2 + r];
    float a2 = rowpart[2 * N2 + r], a3 = rowpart[3 * N2 + r];
    float a4 = 0.f, a5 = 0.f, a6 = 0.f, a7 = 0.f;
    const float* cp = colpart + r;
    for (int k = 1; k <= 113; k += 8) {
        a0 += cp[(size_t)(k + 0) * N2];
        a1 += cp[(size_t)(k + 1) * N2];
        a2 += cp[(size_t)(k + 2) * N2];
        a3 += cp[(size_t)(k + 3) * N2];
        a4 += cp[(size_t)(k + 4) * N2];
        a5 += cp[(size_t)(k + 5) * N2];
        a6 += cp[(size_t)(k + 6) * N2];
        a7 += cp[(size_t)(k + 7) * N2];
    }
    a0 += cp[(size_t)121 * N2]; a1 += cp[(size_t)122 * N2];
    a2 += cp[(size_t)123 * N2]; a3 += cp[(size_t)124 * N2];
    a4 += cp[(size_t)125 * N2]; a5 += cp[(size_t)126 * N2];
    a6 += cp[(size_t)127 * N2];
    float d = ((a0 + a1) + (a2 + a3)) + ((a4 + a5) + (a6 + a7));

    float acc = __builtin_amdgcn_logf(d) * 0.6931471805599453f;   // ln
    if (blockIdx.x == 0) acc -= 4.0f * pospart[t];                // 256 entries
    #pragma unroll
    for (int m = 32; m; m >>= 1) acc += __shfl_xor(acc, m);
    __shared__ float red[4];
    if ((t & 63) == 0) red[t >> 6] = acc;
    __syncthreads();
    if (t == 0)
        atomicAdd(out, (red[0] + red[1] + red[2] + red[3]) *
                       (1.0f / (2.0f * B_ROWS * 5.0f)));
}

extern "C" void kernel_launch(void* const* d_in, const int* in_sizes, int n_in,
                              void* d_out, int out_size, void* d_ws, size_t ws_size,
                              hipStream_t stream) {
    const float* emb_i = (const float*)d_in[0];
    const float* emb_j = (const float*)d_in[1];
    i64* zt        = (i64*)d_ws;                                   // 1 MB tiled fp8
    float* rowpart = (float*)((char*)d_ws + (size_t)N2 * DIMN);    // 128 KB
    float* pospart = rowpart + 4 * N2;                             // 1 KB
    float* colpart = pospart + 256;                                // 4 MB

    normpos_k<<<256, 256, 0, stream>>>(emb_i, emb_j, zt, pospart, (float*)d_out);
    gram_sym_k<<<1024, 256, 0, stream>>>((const char*)zt, rowpart, colpart);
    finalize_k<<<32, 256, 0, stream>>>(rowpart, colpart, pospart, (float*)d_out);
}

// Round 24
// 25.848 us; speedup vs baseline: 2.2470x; 1.1988x over previous
//
#include <hip/hip_runtime.h>
#include <hip/hip_bf16.h>

#define B_ROWS 4096
#define DIMN 128
#define N2 8192
// z pre-scaled by sqrt(log2(e)/TEMP) so mfma output is already the exp2 arg
#define SQRT_CEXP 1.6986436f

using f32x4 = __attribute__((ext_vector_type(4))) float;
using i32x4 = __attribute__((ext_vector_type(4))) int;
using i32x8 = __attribute__((ext_vector_type(8))) int;
typedef long i64;

// f8f6f4-native tiled Z layout:
//   byte addr = Rtile*2048 + lane*32 + b,  lane = (k>>5)*16 + (row&15)
// = the 16x16x128 MFMA A/B fragment; load = 2x global_load_dwordx4.
//
// FINAL CONSTRAINT WEB (R9..R23):
//  - refill slot must never alias a LIVE slot (2-slot flip is sound)
//  - NEVER cap VGPR below natural alloc: spill VMEM corrupts vmcnt -> NaN
//  - 64-row shapes need >170 VGPR naturally -> unusable; 32-row/2-tile fits
//  - neutral: depth-2 prefetch, L1-share maps, XCD maps
//  - regression: LDS staging, cross-XCD fenced fusion, circulant symmetry
//    (halved work but latency-bound regime: slower). gram is latency-bound
//    at the 4-waves/SIMD TLP cap imposed by ~110 VGPR/wave. R18 is the floor
//    of this structural family: REVERTED TO R18 VERBATIM.

// --- 1. normalize+scale+quantize into fragment layout; positives partials ---
// Block 0 also zeroes out[0] (kernel boundary orders it before finalize_k).
__global__ __launch_bounds__(256) void normpos_k(const float* __restrict__ emb_i,
                                                 const float* __restrict__ emb_j,
                                                 i64* __restrict__ zt,
                                                 float* __restrict__ pospart,
                                                 float* __restrict__ out) {
    const int t = threadIdx.x;
    if (blockIdx.x == 0 && t == 0) out[0] = 0.f;
    const int lr = t >> 4;          // local row / pair
    const int s  = t & 15;          // 8-float slice (k = s*8..s*8+7)
    const int p  = blockIdx.x * 16 + lr;
    const float4* ai = (const float4*)(emb_i + (size_t)p * DIMN + s * 8);
    const float4* bj = (const float4*)(emb_j + (size_t)p * DIMN + s * 8);
    float4 a0 = ai[0], a1 = ai[1];
    float4 b0 = bj[0], b1 = bj[1];
    float sa = a0.x*a0.x + a0.y*a0.y + a0.z*a0.z + a0.w*a0.w
             + a1.x*a1.x + a1.y*a1.y + a1.z*a1.z + a1.w*a1.w;
    float sb = b0.x*b0.x + b0.y*b0.y + b0.z*b0.z + b0.w*b0.w
             + b1.x*b1.x + b1.y*b1.y + b1.z*b1.z + b1.w*b1.w;
    float dp = a0.x*b0.x + a0.y*b0.y + a0.z*b0.z + a0.w*b0.w
             + a1.x*b1.x + a1.y*b1.y + a1.z*b1.z + a1.w*b1.w;
    #pragma unroll
    for (int d = 1; d < 16; d <<= 1) {
        sa += __shfl_xor(sa, d);
        sb += __shfl_xor(sb, d);
        dp += __shfl_xor(dp, d);
    }
    float ia = __builtin_amdgcn_rsqf(fmaxf(sa, 1e-24f));
    float ib = __builtin_amdgcn_rsqf(fmaxf(sb, 1e-24f));
    float fa = ia * SQRT_CEXP, fb = ib * SQRT_CEXP;

    int wa0 = __builtin_amdgcn_cvt_pk_fp8_f32(a0.x * fa, a0.y * fa, 0, false);
    wa0     = __builtin_amdgcn_cvt_pk_fp8_f32(a0.z * fa, a0.w * fa, wa0, true);
    int wa1 = __builtin_amdgcn_cvt_pk_fp8_f32(a1.x * fa, a1.y * fa, 0, false);
    wa1     = __builtin_amdgcn_cvt_pk_fp8_f32(a1.z * fa, a1.w * fa, wa1, true);
    i64 qa = ((i64)(unsigned)wa1 << 32) | (unsigned)wa0;
    int wb0 = __builtin_amdgcn_cvt_pk_fp8_f32(b0.x * fb, b0.y * fb, 0, false);
    wb0     = __builtin_amdgcn_cvt_pk_fp8_f32(b0.z * fb, b0.w * fb, wb0, true);
    int wb1 = __builtin_amdgcn_cvt_pk_fp8_f32(b1.x * fb, b1.y * fb, 0, false);
    wb1     = __builtin_amdgcn_cvt_pk_fp8_f32(b1.z * fb, b1.w * fb, wb1, true);
    i64 qb = ((i64)(unsigned)wb1 << 32) | (unsigned)wb0;

    // fragment slot: k-block gk = s>>2, i64-in-lane = s&3, lane = gk*16+lr
    const int slot = ((s >> 2) * 16 + lr) * 4 + (s & 3);
    zt[(size_t)blockIdx.x * 256 + slot] = qa;            // Rtile = b
    zt[(size_t)(256 + blockIdx.x) * 256 + slot] = qb;    // Rtile = 256+b

    __shared__ float red[16];
    if (s == 0) red[lr] = dp * ia * ib;
    __syncthreads();
    if (t == 0) {
        float x = 0.f;
        #pragma unroll
        for (int i = 0; i < 16; ++i) x += red[i];
        pospart[blockIdx.x] = x;
    }
}

// --- step epilogue: ps[m][j] += sum_n exp2(acc), optional diagonal mask ------
template <bool MASK>
__device__ __forceinline__ void accum_step(const f32x4 (&acc)[2][2],
                                           float (&ps)[2][4],
                                           int rb, int cb, int rq, int fr) {
    #pragma unroll
    for (int m = 0; m < 2; ++m)
        #pragma unroll
        for (int n = 0; n < 2; ++n)
            #pragma unroll
            for (int j = 0; j < 4; ++j) {
                float e = __builtin_amdgcn_exp2f(acc[m][n][j]);
                if (MASK) {
                    if (rb + m * 16 + rq + j == cb + n * 16 + fr) e = 0.f;
                }
                ps[m][j] += e;
            }
}

// --- 2. row-panel Gram: MX 16x16x128 MFMA, R14/R18-proven (byte-for-byte) ----
// 1024 blocks x 256 thr (4 waves). Block b: 32-row panel b>>2, col-quarter b&3.
// Wave w: 512 cols = 16 steps of 32 cols (2 tiles, 4 MFMA). 2-slot flip,
// refill the OTHER slot BEFORE the wait, vmcnt(4) steady state, never 0
// mid-loop, sched_barrier fences. Default bounds: natural VGPR, no spill.
__global__ __launch_bounds__(256) void gram_k(const char* __restrict__ zt,
                                              float* __restrict__ rowpart) {
    const int t = threadIdx.x;
    const int lane = t & 63;
    const int w = t >> 6;               // 0..3
    const int p = blockIdx.x >> 2;      // 32-row panel, 0..255
    const int e = blockIdx.x & 3;       // col quarter
    const int rb = p * 32;
    const int fr = lane & 15;
    const int rq = (lane >> 4) * 4;

    const char* pa = zt + (size_t)(p * 2) * 2048 + lane * 32;
    const char* pb = zt + (size_t)(e * 128 + w * 32) * 2048 + lane * 32;

    // prologue: A (4 loads) + B slot0 (4 loads)
    i32x4 Alo[2], Ahi[2];
    #pragma unroll
    for (int m = 0; m < 2; ++m) {
        asm volatile("global_load_dwordx4 %0, %1, off"
                     : "=v"(Alo[m]) : "v"(pa + (size_t)m * 2048));
        asm volatile("global_load_dwordx4 %0, %1, off offset:16"
                     : "=v"(Ahi[m]) : "v"(pa + (size_t)m * 2048));
    }
    i32x4 Blo[2][2], Bhi[2][2];
    #pragma unroll
    for (int n = 0; n < 2; ++n) {
        asm volatile("global_load_dwordx4 %0, %1, off"
                     : "=v"(Blo[0][n]) : "v"(pb + (size_t)n * 2048));
        asm volatile("global_load_dwordx4 %0, %1, off offset:16"
                     : "=v"(Bhi[0][n]) : "v"(pb + (size_t)n * 2048));
    }
    asm volatile("s_waitcnt vmcnt(4)" ::: "memory");    // A done; B0 in flight
    __builtin_amdgcn_sched_barrier(0);
    i32x8 A8[2];
    #pragma unroll
    for (int m = 0; m < 2; ++m)
        A8[m] = __builtin_shufflevector(Alo[m], Ahi[m], 0, 1, 2, 3, 4, 5, 6, 7);

    float ps[2][4] = {};
    #pragma unroll
    for (int s = 0; s < 16; ++s) {
        if (s < 15) {                   // refill OTHER slot, then wait (R14 order)
            const char* pn = pb + (size_t)(s + 1) * 4096;
            #pragma unroll
            for (int n = 0; n < 2; ++n) {
                asm volatile("global_load_dwordx4 %0, %1, off"
                             : "=v"(Blo[(s + 1) & 1][n]) : "v"(pn + (size_t)n * 2048));
                asm volatile("global_load_dwordx4 %0, %1, off offset:16"
                             : "=v"(Bhi[(s + 1) & 1][n]) : "v"(pn + (size_t)n * 2048));
            }
            asm volatile("s_waitcnt vmcnt(4)" ::: "memory");  // slot s done, s+1 flying
        } else {
            asm volatile("s_waitcnt vmcnt(0)" ::: "memory");
        }
        __builtin_amdgcn_sched_barrier(0);                    // rule #18 fence

        f32x4 acc[2][2] = {};
        __builtin_amdgcn_s_setprio(1);
        #pragma unroll
        for (int n = 0; n < 2; ++n) {
            i32x8 B8 = __builtin_shufflevector(Blo[s & 1][n], Bhi[s & 1][n],
                                               0, 1, 2, 3, 4, 5, 6, 7);
            #pragma unroll
            for (int m = 0; m < 2; ++m)
                acc[m][n] = __builtin_amdgcn_mfma_scale_f32_16x16x128_f8f6f4(
                    A8[m], B8, acc[m][n], 0, 0,          // cbsz=fp8, blgp=fp8
                    0, 0x7f7f7f7f, 0, 0x7f7f7f7f);       // unit scales (e8m0=127)
        }
        __builtin_amdgcn_s_setprio(0);

        const int cb = e * 2048 + w * 512 + s * 32;
        if (cb == rb) accum_step<true >(acc, ps, rb, cb, rq, fr);
        else          accum_step<false>(acc, ps, rb, cb, rq, fr);
    }

    // 16-lane reduce per row, cross-wave LDS reduce, store this quarter's part
    #pragma unroll
    for (int m = 0; m < 2; ++m)
        #pragma unroll
        for (int j = 0; j < 4; ++j) {
            float v = ps[m][j];
            #pragma unroll
            for (int d = 1; d < 16; d <<= 1) v += __shfl_xor(v, d);
            ps[m][j] = v;
        }
    __shared__ float red[4][32];
    if (fr == 0) {
        #pragma unroll
        for (int m = 0; m < 2; ++m)
            #pragma unroll
            for (int j = 0; j < 4; ++j)
                red[w][m * 16 + rq + j] = ps[m][j];
    }
    __syncthreads();
    if (t < 32)
        rowpart[e * N2 + rb + t] = red[0][t] + red[1][t] + red[2][t] + red[3][t];
}

// --- 3. finalize, distributed: 8 blocks x 1024 thr, atomicAdd into out -------
__global__ void finalize_k(const float* __restrict__ rowpart,
                           const float* __restrict__ pospart,
                           float* __restrict__ out) {
    const int t = threadIdx.x;
    const int r = blockIdx.x * 1024 + t;
    float d = rowpart[r] + rowpart[N2 + r] + rowpart[2 * N2 + r] + rowpart[3 * N2 + r];
    float acc = __builtin_amdgcn_logf(d) * 0.6931471805599453f;   // ln
    if (blockIdx.x == 0 && t < 256) acc -= 4.0f * pospart[t];
    #pragma unroll
    for (int m = 32; m; m >>= 1) acc += __shfl_xor(acc, m);
    __shared__ float red[16];
    if ((t & 63) == 0) red[t >> 6] = acc;
    __syncthreads();
    if (t == 0) {
        float x = 0.f;
        #pragma unroll
        for (int i = 0; i < 16; ++i) x += red[i];
        atomicAdd(out, x * (1.0f / (2.0f * B_ROWS * 5.0f)));
    }
}

extern "C" void kernel_launch(void* const* d_in, const int* in_sizes, int n_in,
                              void* d_out, int out_size, void* d_ws, size_t ws_size,
                              hipStream_t stream) {
    const float* emb_i = (const float*)d_in[0];
    const float* emb_j = (const float*)d_in[1];
    i64* zt        = (i64*)d_ws;                                   // 1 MB tiled fp8
    float* rowpart = (float*)((char*)d_ws + (size_t)N2 * DIMN);    // 128 KB (4 parts)
    float* pospart = rowpart + 4 * N2;                             // 1 KB

    normpos_k<<<256, 256, 0, stream>>>(emb_i, emb_j, zt, pospart, (float*)d_out);
    gram_k<<<1024, 256, 0, stream>>>((const char*)zt, rowpart);
    finalize_k<<<8, 1024, 0, stream>>>(rowpart, pospart, (float*)d_out);
}